// Round 15
// baseline (144.379 us; speedup 1.0000x reference)
//
#include <hip/hip_runtime.h>
#include <cstdint>

#define NFEAT 4096
#define NHALF 2048
#define DDIM  512
#define QROWS 32768

typedef unsigned short u16;
typedef unsigned char  u8;
typedef unsigned int   u32;
typedef unsigned long long u64;

typedef float  f32x16_t __attribute__((ext_vector_type(16)));
typedef int    i32x4_t  __attribute__((ext_vector_type(4)));
typedef int    i32x8_t  __attribute__((ext_vector_type(8)));

typedef const __attribute__((address_space(1))) void* gas_ptr;
typedef __attribute__((address_space(3))) void* las_ptr;

// monotonic unsigned encoding of float (no NaN/Inf expected)
__device__ __forceinline__ u32 fkey(float f) {
  u32 u = __float_as_uint(f);
  return (u & 0x80000000u) ? ~u : (u | 0x80000000u);
}

// ---------------- kernel 1: l2-normalize rows -> TILED fp8(e4m3) --------------
// fp8 buffers stored PRE-TILED in the GEMM's fragment order: addr(row,k) =
// (row>>5)*16384 + (k>>6)*2048 + ((k>>5)&1)*1024 + ((k>>4)&1)*512 +
// (row&31)*16 + (k&15).  (verified R11/R12, absmax 0.0)
__global__ void k_norm(const float* __restrict__ zi, const float* __restrict__ zj,
                       const float* __restrict__ queue,
                       u8* __restrict__ feat8T, u8* __restrict__ queue8T) {
  int gw = (int)((blockIdx.x * blockDim.x + threadIdx.x) >> 6);
  int lane = threadIdx.x & 63;
  const float* src; u8* dstT; int r31;
  if (gw < NFEAT) {
    src = (gw < NHALF) ? (zi + (size_t)gw * DDIM) : (zj + (size_t)(gw - NHALF) * DDIM);
    dstT = feat8T + (size_t)(gw >> 5) * 16384; r31 = gw & 31;
  } else {
    int r = gw - NFEAT;
    src = queue + (size_t)r * DDIM;
    dstT = queue8T + (size_t)(r >> 5) * 16384; r31 = r & 31;
  }
  float4 v0 = reinterpret_cast<const float4*>(src)[lane * 2];
  float4 v1 = reinterpret_cast<const float4*>(src)[lane * 2 + 1];
  float ss = v0.x*v0.x + v0.y*v0.y + v0.z*v0.z + v0.w*v0.w
           + v1.x*v1.x + v1.y*v1.y + v1.z*v1.z + v1.w*v1.w;
  #pragma unroll
  for (int off = 32; off >= 1; off >>= 1) ss += __shfl_xor(ss, off);
  float inv = 1.0f / fmaxf(sqrtf(ss), 1e-12f);
  float n0 = v0.x*inv, n1 = v0.y*inv, n2 = v0.z*inv, n3 = v0.w*inv;
  float n4 = v1.x*inv, n5 = v1.y*inv, n6 = v1.z*inv, n7 = v1.w*inv;
  u32 p01, p23, p45, p67;
  asm("v_cvt_pk_fp8_f32 %0, %1, %2" : "=v"(p01) : "v"(n0), "v"(n1));
  asm("v_cvt_pk_fp8_f32 %0, %1, %2" : "=v"(p23) : "v"(n2), "v"(n3));
  asm("v_cvt_pk_fp8_f32 %0, %1, %2" : "=v"(p45) : "v"(n4), "v"(n5));
  asm("v_cvt_pk_fp8_f32 %0, %1, %2" : "=v"(p67) : "v"(n6), "v"(n7));
  uint2 w8;
  w8.x = (p01 & 0xFFFFu) | (p23 << 16);
  w8.y = (p45 & 0xFFFFu) | (p67 << 16);
  size_t toff = (size_t)(lane >> 3) * 2048 + ((lane >> 2) & 1) * 1024
              + ((lane >> 1) & 1) * 512 + r31 * 16 + (lane & 1) * 8;
  *reinterpret_cast<uint2*>(dstT + toff) = w8;
}

#define SB0() __builtin_amdgcn_sched_barrier(0)
#define LGKM0_SB() do { asm volatile("s_waitcnt lgkmcnt(0)" ::: "memory"); SB0(); } while (0)
#define VMCNT4() asm volatile("s_waitcnt vmcnt(4)" ::: "memory")
#define VMCNT0() asm volatile("s_waitcnt vmcnt(0)" ::: "memory")
#define SBAR() __builtin_amdgcn_s_barrier()
#define RD(dst, base, off) asm volatile("ds_read_b128 %0, %1 offset:" off \
                                        : "=v"(dst) : "v"(base))

// ---------------- shared fp8 MX tile engine (R12, verified absmax 0.0) --------
// Block 4 waves/256 thr, tile 128x128, wave 64x64 (2m x 2n of 32x32x64 f8f6f4,
// acc 64 regs). FRAGMENT-ORDERED LDS slot L = mb*128 + hi*64 + s*32 + r31
// (conflict-free). Tile 16KB, ring-3 = 48KB -> 3 blocks/CU. Ledger: stage t+2
// during t into buf (t+2)%3 = (t-1)%3 (reads of t-1 lgkm-confirmed before its
// boundary barrier -> WAR safe); boundary vmcnt(4) proves stage(t+1) landed;
// t=5 boundary vmcnt(0); t=6 boundary barrier-only.
#define MFMA8(ACC, AV, BV) \
  ACC = __builtin_amdgcn_mfma_scale_f32_32x32x64_f8f6f4(AV, BV, ACC, 0, 0, 0, \
        0x7F7F7F7F, 0, 0x7F7F7F7F)

#define FP8_TILE(XA, XB) do { \
    i32x4_t a00, a01, a10, a11, b00, b01, b10, b11; \
    RD(a00, XA, "0"); RD(a01, XA, "512"); \
    RD(a10, XA, "2048"); RD(a11, XA, "2560"); \
    RD(b00, XB, "0"); RD(b01, XB, "512"); \
    RD(b10, XB, "2048"); RD(b11, XB, "2560"); \
    LGKM0_SB(); \
    i32x8_t A0 = __builtin_shufflevector(a00, a01, 0, 1, 2, 3, 4, 5, 6, 7); \
    i32x8_t A1 = __builtin_shufflevector(a10, a11, 0, 1, 2, 3, 4, 5, 6, 7); \
    i32x8_t B0 = __builtin_shufflevector(b00, b01, 0, 1, 2, 3, 4, 5, 6, 7); \
    i32x8_t B1 = __builtin_shufflevector(b10, b11, 0, 1, 2, 3, 4, 5, 6, 7); \
    __builtin_amdgcn_s_setprio(1); \
    MFMA8(acc00, A0, B0); \
    MFMA8(acc01, A0, B1); \
    MFMA8(acc10, A1, B0); \
    MFMA8(acc11, A1, B1); \
    __builtin_amdgcn_s_setprio(0); \
  } while (0)

#define FP8_MAIN_LOOP() do { \
  stage(0, 0); stage(1, 1); \
  VMCNT4(); \
  SBAR(); \
  _Pragma("unroll") \
  for (int t = 0; t < 8; t++) { \
    if (t <= 5) stage((t + 2) % 3, t + 2); \
    const u32 bb = (u32)((t % 3) * 16384); \
    FP8_TILE(aAd + bb, bAd + bb); \
    if (t < 7) { \
      if (t <= 5) VMCNT4(); else VMCNT0(); \
      SBAR(); \
    } \
  } } while (0)

// ---------------- kernel 2: fp8 GEMM queue @ feat^T + fused col-argmax --------
// A = queue tile (M), B = feat tile (N); per-feature argmax over queue rows is
// lane-local (col = lane) in-register scan + one shfl_xor(32). Verified R12.
__global__ __launch_bounds__(256, 2) void k_argmax_gemm8(
    const u8* __restrict__ feat8T, const u8* __restrict__ queue8T,
    u64* __restrict__ part) {
  __shared__ u8 lds[49152];
  const int tid = threadIdx.x;
  const int w = tid >> 6, lane = tid & 63;
  const int wr = w >> 1, wc = w & 1;
  const int l31 = lane & 31, hi = lane >> 5;
  const int bid = (int)blockIdx.x;
  const int wg = (bid & 7) * 1024 + (bid >> 3);  // bijective XCD swizzle (8192 = 8x1024)
  const int mt = wg >> 5, ft = wg & 31;          // ft fastest: queue slice L2-resident
  const int brow = mt * 128, bcol = ft * 128;

  const u8* pA = queue8T + (size_t)(brow >> 5) * 16384 + (tid >> 7) * 16384 + (tid & 127) * 16;
  const u8* pB = feat8T  + (size_t)(bcol >> 5) * 16384 + (tid >> 7) * 16384 + (tid & 127) * 16;
  const u32 dA = (u32)(size_t)(las_ptr)&lds[tid * 16];
  const u32 dB = dA + 8192;

  const u32 aAd = (u32)(size_t)(las_ptr)&lds[wr * 4096 + hi * 1024 + l31 * 16];
  const u32 bAd = (u32)(size_t)(las_ptr)&lds[8192 + wc * 4096 + hi * 1024 + l31 * 16];

  f32x16_t acc00 = {}, acc01 = {}, acc10 = {}, acc11 = {};

  auto stage = [&](int b, int t) {
    const u32 base = (u32)(b * 16384);
    __builtin_amdgcn_global_load_lds((gas_ptr)(pA + t * 2048),         (las_ptr)(size_t)(dA + base), 16, 0, 0);
    __builtin_amdgcn_global_load_lds((gas_ptr)(pA + 32768 + t * 2048), (las_ptr)(size_t)(dA + base + 4096), 16, 0, 0);
    __builtin_amdgcn_global_load_lds((gas_ptr)(pB + t * 2048),         (las_ptr)(size_t)(dB + base), 16, 0, 0);
    __builtin_amdgcn_global_load_lds((gas_ptr)(pB + 32768 + t * 2048), (las_ptr)(size_t)(dB + base + 4096), 16, 0, 0);
  };

  FP8_MAIN_LOOP();

  // epilogue: per-feature (column = lane) argmax over this wave's 64 queue rows.
  // C/D 32x32: col = lane&31 (feat), row = (reg&3) + 8*(reg>>2) + 4*hi (+m*32).
  const int mslot = mt * 2 + wr;
  const int fbase = bcol + wc * 64 + l31;
  #pragma unroll
  for (int n = 0; n < 2; n++) {
    float bv = -3.0e38f; int br = 0;
    #pragma unroll
    for (int m = 0; m < 2; m++) {
      #pragma unroll
      for (int reg = 0; reg < 16; reg++) {
        float v = n == 0 ? (m == 0 ? acc00[reg] : acc10[reg])
                         : (m == 0 ? acc01[reg] : acc11[reg]);
        int lr = m * 32 + (reg & 3) + 8 * (reg >> 2);   // ascending over (m,reg)
        if (v > bv) { bv = v; br = lr; }
      }
    }
    u32 q = (u32)(brow + wr * 64 + br + 4 * hi);
    u64 key = ((u64)fkey(bv) << 32) | (u64)(0xFFFFFFFFu - q);
    u64 o = __shfl_xor(key, 32);
    key = key > o ? key : o;
    if (hi == 0) part[(size_t)(fbase + n * 32) * 512 + mslot] = key;
  }
}

// ---------------- kernel 3: reduce argmax partials -> nn_idx ----------------
__global__ void k_argmax_reduce(const u64* __restrict__ part, int* __restrict__ nnidx) {
  int row = (int)((blockIdx.x * blockDim.x + threadIdx.x) >> 6);
  int lane = threadIdx.x & 63;
  const u64* p = part + (size_t)row * 512;
  u64 best = 0;
  #pragma unroll
  for (int i = 0; i < 8; i++) { u64 v = p[lane * 8 + i]; best = best > v ? best : v; }
  #pragma unroll
  for (int off = 1; off < 64; off <<= 1) { u64 o = __shfl_xor(best, off); best = best > o ? best : o; }
  if (lane == 0) nnidx[row] = (int)(0xFFFFFFFFu - (u32)(best & 0xFFFFFFFFu));
}

// ---------------- kernel 4: fp8 GEMM feat @ nn^T + fused col-lse + positives --
// Transposed like k_argmax_gemm8: A = feat tile (M, scanned), B = GATHERED nn
// rows (N = lanes). C[i][j] = feat_i . nn_j = sim[j][i]; per-row lse of sim =
// per-COLUMN of C = lane-local 2-pass max/sum-exp scan over the lane's 32
// M-rows, THEN hi-pair merge via shfl_xor(32) (R14 bug: each lane covers only
// half the 64 rows; the pair shares column j). pos[j] = C[j^2048][j] captured
// in-scan (unique writer across the pair). lsep[j][mt*2+wr] -> k_lse.
__global__ __launch_bounds__(256, 2) void k_sim_gemm8(
    const u8* __restrict__ feat8T, const u8* __restrict__ queue8T,
    const int* __restrict__ nnidx,
    float2* __restrict__ lsep, float* __restrict__ pos) {
  __shared__ u8 lds[49152];
  const int tid = threadIdx.x;
  const int w = tid >> 6, lane = tid & 63;
  const int wr = w >> 1, wc = w & 1;
  const int l31 = lane & 31, hi = lane >> 5;
  const int bid = (int)blockIdx.x;
  const int wg = (bid & 7) * 128 + (bid >> 3);   // bijective XCD swizzle (1024 = 8x128)
  const int mt = wg >> 5, nt = wg & 31;
  const int mtb = mt * 128, ntb = nt * 128;

  // A = feat (contiguous pre-tiled)
  const u8* pA = feat8T + (size_t)(mtb >> 5) * 16384 + (tid >> 7) * 16384 + (tid & 127) * 16;
  // B = gathered nn rows: slot L=tid covers (mb=tid>>7, hi_k=(tid>>6)&1,
  // s=(tid>>5)&1, r31=tid&31); slot tid+256 covers mb+2. Source = tiled addr
  // of (nnidx row, k sub-slot) -- per-lane glds source is allowed.
  const int g0 = nnidx[ntb + (tid >> 7) * 32 + (tid & 31)];
  const int g1 = nnidx[ntb + (tid >> 7) * 32 + 64 + (tid & 31)];
  const int sub = ((tid >> 6) & 1) * 1024 + ((tid >> 5) & 1) * 512;
  const u8* pB0 = queue8T + (size_t)(g0 >> 5) * 16384 + sub + (g0 & 31) * 16;
  const u8* pB1 = queue8T + (size_t)(g1 >> 5) * 16384 + sub + (g1 & 31) * 16;
  const u32 dA = (u32)(size_t)(las_ptr)&lds[tid * 16];
  const u32 dB = dA + 8192;

  const u32 aAd = (u32)(size_t)(las_ptr)&lds[wr * 4096 + hi * 1024 + l31 * 16];
  const u32 bAd = (u32)(size_t)(las_ptr)&lds[8192 + wc * 4096 + hi * 1024 + l31 * 16];

  f32x16_t acc00 = {}, acc01 = {}, acc10 = {}, acc11 = {};

  auto stage = [&](int b, int t) {
    const u32 base = (u32)(b * 16384);
    __builtin_amdgcn_global_load_lds((gas_ptr)(pA + t * 2048),         (las_ptr)(size_t)(dA + base), 16, 0, 0);
    __builtin_amdgcn_global_load_lds((gas_ptr)(pA + 32768 + t * 2048), (las_ptr)(size_t)(dA + base + 4096), 16, 0, 0);
    __builtin_amdgcn_global_load_lds((gas_ptr)(pB0 + t * 2048),        (las_ptr)(size_t)(dB + base), 16, 0, 0);
    __builtin_amdgcn_global_load_lds((gas_ptr)(pB1 + t * 2048),        (las_ptr)(size_t)(dB + base + 4096), 16, 0, 0);
  };

  FP8_MAIN_LOOP();

  // epilogue: per-column (lane pair = nn row j) lse over 64 feat rows,
  // scale by 1/T=2, diag mask, positive capture, hi-pair online-softmax merge.
  const int mslot = mt * 2 + wr;
  const int ibase = mtb + wr * 64 + 4 * hi;
  #pragma unroll
  for (int n = 0; n < 2; n++) {
    const int j = ntb + wc * 64 + n * 32 + l31;
    const int jp = j ^ NHALF;
    float mx = -3.0e38f;
    #pragma unroll
    for (int m = 0; m < 2; m++) {
      #pragma unroll
      for (int reg = 0; reg < 16; reg++) {
        float v = (n == 0 ? (m == 0 ? acc00[reg] : acc10[reg])
                          : (m == 0 ? acc01[reg] : acc11[reg])) * 2.0f;
        int i = ibase + m * 32 + (reg & 3) + 8 * (reg >> 2);
        if (i == jp) pos[j] = v;            // positive (unique writer; jp != j)
        if (i == j) v = -1.0e30f;           // diag mask
        mx = fmaxf(mx, v);
      }
    }
    float sm = 0.f;
    #pragma unroll
    for (int m = 0; m < 2; m++) {
      #pragma unroll
      for (int reg = 0; reg < 16; reg++) {
        float v = (n == 0 ? (m == 0 ? acc00[reg] : acc10[reg])
                          : (m == 0 ? acc01[reg] : acc11[reg])) * 2.0f;
        int i = ibase + m * 32 + (reg & 3) + 8 * (reg >> 2);
        if (i == j) v = -1.0e30f;
        sm += __expf(v - mx);
      }
    }
    // merge the hi pair (each lane scanned only 32 of the 64 rows)
    float mo = __shfl_xor(mx, 32);
    float so = __shfl_xor(sm, 32);
    float M = fmaxf(mx, mo);
    sm = sm * __expf(mx - M) + so * __expf(mo - M);
    if (hi == 0) lsep[(size_t)j * 64 + mslot] = make_float2(M, sm);
  }
}

// ---------------- kernel 5: per-row logsumexp merge ----------------
__global__ void k_lse(const float2* __restrict__ lsep, float* __restrict__ lse) {
  int row = (int)((blockIdx.x * blockDim.x + threadIdx.x) >> 6);
  int lane = threadIdx.x & 63;
  float2 p = lsep[(size_t)row * 64 + lane];
  float m = p.x, s = p.y;
  #pragma unroll
  for (int off = 1; off < 64; off <<= 1) {
    float mo = __shfl_xor(m, off), so = __shfl_xor(s, off);
    float M = fmaxf(m, mo);
    s = s * __expf(m - M) + so * __expf(mo - M);
    m = M;
  }
  if (lane == 0) lse[row] = m + __logf(s);
}

// ---------------- kernel 6: final scalar ----------------
__global__ void k_final(const float* __restrict__ lse, const float* __restrict__ pos,
                        float* __restrict__ out) {
  __shared__ float red[4];
  int tid = threadIdx.x;
  float a = 0.f;
  for (int i = tid; i < NFEAT; i += 256) a += lse[i] - pos[i];
  #pragma unroll
  for (int off = 32; off >= 1; off >>= 1) a += __shfl_xor(a, off);
  if ((tid & 63) == 0) red[tid >> 6] = a;
  __syncthreads();
  if (tid == 0) out[0] = (red[0] + red[1] + red[2] + red[3]) / (float)NFEAT;
}

extern "C" void kernel_launch(void* const* d_in, const int* in_sizes, int n_in,
                              void* d_out, int out_size, void* d_ws, size_t ws_size,
                              hipStream_t stream) {
  const float* zi    = (const float*)d_in[0];
  const float* zj    = (const float*)d_in[1];
  const float* queue = (const float*)d_in[2];
  float* out = (float*)d_out;
  char* ws = (char*)d_ws;

  // ws layout (bytes):
  u8*     queue8T = (u8*)(ws + 0);               // 32768*512   = 16777216
  u8*     feat8T  = (u8*)(ws + 16777216);        // 4096*512    = 2097152
  u64*    part    = (u64*)(ws + 18874368);       // 4096*512*8  = 16777216
  int*    nnidx   = (int*)(ws + 35651584);       // 4096*4      = 16384
  float2* lsep    = (float2*)(ws + 35667968);    // 4096*64*8   = 2097152
  float*  pos     = (float*)(ws + 37765120);     // 4096*4      = 16384
  float*  lse     = (float*)(ws + 37781504);     // 4096*4      = 16384
  // total = 37797888 bytes (~36 MB)

  k_norm<<<9216, 256, 0, stream>>>(zi, zj, queue, feat8T, queue8T);
  k_argmax_gemm8<<<8192, 256, 0, stream>>>(feat8T, queue8T, part);
  k_argmax_reduce<<<1024, 256, 0, stream>>>(part, nnidx);
  k_sim_gemm8<<<1024, 256, 0, stream>>>(feat8T, queue8T, nnidx, lsep, pos);
  k_lse<<<1024, 256, 0, stream>>>(lsep, lse);
  k_final<<<1, 256, 0, stream>>>(lse, pos, out);
}

// Round 16
// 113.974 us; speedup vs baseline: 1.2668x; 1.2668x over previous
//
#include <hip/hip_runtime.h>
#include <cstdint>

#define NFEAT 4096
#define NHALF 2048
#define DDIM  512
#define QROWS 32768

typedef unsigned short u16;
typedef unsigned char  u8;
typedef unsigned int   u32;
typedef unsigned long long u64;

typedef float  f32x16_t __attribute__((ext_vector_type(16)));
typedef int    i32x4_t  __attribute__((ext_vector_type(4)));
typedef int    i32x8_t  __attribute__((ext_vector_type(8)));

typedef const __attribute__((address_space(1))) void* gas_ptr;
typedef __attribute__((address_space(3))) void* las_ptr;

// monotonic unsigned encoding of float (no NaN/Inf expected)
__device__ __forceinline__ u32 fkey(float f) {
  u32 u = __float_as_uint(f);
  return (u & 0x80000000u) ? ~u : (u | 0x80000000u);
}

// ---------------- kernel 1: l2-normalize rows -> TILED fp8(e4m3) --------------
// fp8 buffers stored PRE-TILED in the GEMM's fragment order: addr(row,k) =
// (row>>5)*16384 + (k>>6)*2048 + ((k>>5)&1)*1024 + ((k>>4)&1)*512 +
// (row&31)*16 + (k&15).  (verified R11/R12, absmax 0.0)
__global__ void k_norm(const float* __restrict__ zi, const float* __restrict__ zj,
                       const float* __restrict__ queue,
                       u8* __restrict__ feat8T, u8* __restrict__ queue8T) {
  int gw = (int)((blockIdx.x * blockDim.x + threadIdx.x) >> 6);
  int lane = threadIdx.x & 63;
  const float* src; u8* dstT; int r31;
  if (gw < NFEAT) {
    src = (gw < NHALF) ? (zi + (size_t)gw * DDIM) : (zj + (size_t)(gw - NHALF) * DDIM);
    dstT = feat8T + (size_t)(gw >> 5) * 16384; r31 = gw & 31;
  } else {
    int r = gw - NFEAT;
    src = queue + (size_t)r * DDIM;
    dstT = queue8T + (size_t)(r >> 5) * 16384; r31 = r & 31;
  }
  float4 v0 = reinterpret_cast<const float4*>(src)[lane * 2];
  float4 v1 = reinterpret_cast<const float4*>(src)[lane * 2 + 1];
  float ss = v0.x*v0.x + v0.y*v0.y + v0.z*v0.z + v0.w*v0.w
           + v1.x*v1.x + v1.y*v1.y + v1.z*v1.z + v1.w*v1.w;
  #pragma unroll
  for (int off = 32; off >= 1; off >>= 1) ss += __shfl_xor(ss, off);
  float inv = 1.0f / fmaxf(sqrtf(ss), 1e-12f);
  float n0 = v0.x*inv, n1 = v0.y*inv, n2 = v0.z*inv, n3 = v0.w*inv;
  float n4 = v1.x*inv, n5 = v1.y*inv, n6 = v1.z*inv, n7 = v1.w*inv;
  u32 p01, p23, p45, p67;
  asm("v_cvt_pk_fp8_f32 %0, %1, %2" : "=v"(p01) : "v"(n0), "v"(n1));
  asm("v_cvt_pk_fp8_f32 %0, %1, %2" : "=v"(p23) : "v"(n2), "v"(n3));
  asm("v_cvt_pk_fp8_f32 %0, %1, %2" : "=v"(p45) : "v"(n4), "v"(n5));
  asm("v_cvt_pk_fp8_f32 %0, %1, %2" : "=v"(p67) : "v"(n6), "v"(n7));
  uint2 w8;
  w8.x = (p01 & 0xFFFFu) | (p23 << 16);
  w8.y = (p45 & 0xFFFFu) | (p67 << 16);
  size_t toff = (size_t)(lane >> 3) * 2048 + ((lane >> 2) & 1) * 1024
              + ((lane >> 1) & 1) * 512 + r31 * 16 + (lane & 1) * 8;
  *reinterpret_cast<uint2*>(dstT + toff) = w8;
}

#define SB0() __builtin_amdgcn_sched_barrier(0)
#define LGKM0_SB() do { asm volatile("s_waitcnt lgkmcnt(0)" ::: "memory"); SB0(); } while (0)
#define VMCNT4() asm volatile("s_waitcnt vmcnt(4)" ::: "memory")
#define VMCNT0() asm volatile("s_waitcnt vmcnt(0)" ::: "memory")
#define SBAR() __builtin_amdgcn_s_barrier()
#define RD(dst, base, off) asm volatile("ds_read_b128 %0, %1 offset:" off \
                                        : "=v"(dst) : "v"(base))

// ---------------- shared fp8 MX tile engine (R12, verified absmax 0.0) --------
// Block 4 waves/256 thr, tile 128x128, wave 64x64 (2m x 2n of 32x32x64 f8f6f4,
// acc 64 regs). FRAGMENT-ORDERED LDS slot L = mb*128 + hi*64 + s*32 + r31
// (conflict-free). Tile 16KB, ring-3 = 48KB -> 3 blocks/CU. Ledger: stage t+2
// during t into buf (t+2)%3 = (t-1)%3 (reads of t-1 lgkm-confirmed before its
// boundary barrier -> WAR safe); boundary vmcnt(4) proves stage(t+1) landed;
// t=5 boundary vmcnt(0); t=6 boundary barrier-only.
#define MFMA8(ACC, AV, BV) \
  ACC = __builtin_amdgcn_mfma_scale_f32_32x32x64_f8f6f4(AV, BV, ACC, 0, 0, 0, \
        0x7F7F7F7F, 0, 0x7F7F7F7F)

#define FP8_TILE(XA, XB) do { \
    i32x4_t a00, a01, a10, a11, b00, b01, b10, b11; \
    RD(a00, XA, "0"); RD(a01, XA, "512"); \
    RD(a10, XA, "2048"); RD(a11, XA, "2560"); \
    RD(b00, XB, "0"); RD(b01, XB, "512"); \
    RD(b10, XB, "2048"); RD(b11, XB, "2560"); \
    LGKM0_SB(); \
    i32x8_t A0 = __builtin_shufflevector(a00, a01, 0, 1, 2, 3, 4, 5, 6, 7); \
    i32x8_t A1 = __builtin_shufflevector(a10, a11, 0, 1, 2, 3, 4, 5, 6, 7); \
    i32x8_t B0 = __builtin_shufflevector(b00, b01, 0, 1, 2, 3, 4, 5, 6, 7); \
    i32x8_t B1 = __builtin_shufflevector(b10, b11, 0, 1, 2, 3, 4, 5, 6, 7); \
    __builtin_amdgcn_s_setprio(1); \
    MFMA8(acc00, A0, B0); \
    MFMA8(acc01, A0, B1); \
    MFMA8(acc10, A1, B0); \
    MFMA8(acc11, A1, B1); \
    __builtin_amdgcn_s_setprio(0); \
  } while (0)

#define FP8_MAIN_LOOP() do { \
  stage(0, 0); stage(1, 1); \
  VMCNT4(); \
  SBAR(); \
  _Pragma("unroll") \
  for (int t = 0; t < 8; t++) { \
    if (t <= 5) stage((t + 2) % 3, t + 2); \
    const u32 bb = (u32)((t % 3) * 16384); \
    FP8_TILE(aAd + bb, bAd + bb); \
    if (t < 7) { \
      if (t <= 5) VMCNT4(); else VMCNT0(); \
      SBAR(); \
    } \
  } } while (0)

// ---------------- kernel 2: fp8 GEMM queue @ feat^T + fused col-argmax --------
// A = queue tile (M), B = feat tile (N); per-feature argmax over queue rows is
// lane-local (col = lane) in-register scan + one shfl_xor(32). Verified R12.
__global__ __launch_bounds__(256, 2) void k_argmax_gemm8(
    const u8* __restrict__ feat8T, const u8* __restrict__ queue8T,
    u64* __restrict__ part) {
  __shared__ u8 lds[49152];
  const int tid = threadIdx.x;
  const int w = tid >> 6, lane = tid & 63;
  const int wr = w >> 1, wc = w & 1;
  const int l31 = lane & 31, hi = lane >> 5;
  const int bid = (int)blockIdx.x;
  const int wg = (bid & 7) * 1024 + (bid >> 3);  // bijective XCD swizzle (8192 = 8x1024)
  const int mt = wg >> 5, ft = wg & 31;          // ft fastest: queue slice L2-resident
  const int brow = mt * 128, bcol = ft * 128;

  const u8* pA = queue8T + (size_t)(brow >> 5) * 16384 + (tid >> 7) * 16384 + (tid & 127) * 16;
  const u8* pB = feat8T  + (size_t)(bcol >> 5) * 16384 + (tid >> 7) * 16384 + (tid & 127) * 16;
  const u32 dA = (u32)(size_t)(las_ptr)&lds[tid * 16];
  const u32 dB = dA + 8192;

  const u32 aAd = (u32)(size_t)(las_ptr)&lds[wr * 4096 + hi * 1024 + l31 * 16];
  const u32 bAd = (u32)(size_t)(las_ptr)&lds[8192 + wc * 4096 + hi * 1024 + l31 * 16];

  f32x16_t acc00 = {}, acc01 = {}, acc10 = {}, acc11 = {};

  auto stage = [&](int b, int t) {
    const u32 base = (u32)(b * 16384);
    __builtin_amdgcn_global_load_lds((gas_ptr)(pA + t * 2048),         (las_ptr)(size_t)(dA + base), 16, 0, 0);
    __builtin_amdgcn_global_load_lds((gas_ptr)(pA + 32768 + t * 2048), (las_ptr)(size_t)(dA + base + 4096), 16, 0, 0);
    __builtin_amdgcn_global_load_lds((gas_ptr)(pB + t * 2048),         (las_ptr)(size_t)(dB + base), 16, 0, 0);
    __builtin_amdgcn_global_load_lds((gas_ptr)(pB + 32768 + t * 2048), (las_ptr)(size_t)(dB + base + 4096), 16, 0, 0);
  };

  FP8_MAIN_LOOP();

  // epilogue: per-feature (column = lane) argmax over this wave's 64 queue rows.
  // C/D 32x32: col = lane&31 (feat), row = (reg&3) + 8*(reg>>2) + 4*hi (+m*32).
  const int mslot = mt * 2 + wr;
  const int fbase = bcol + wc * 64 + l31;
  #pragma unroll
  for (int n = 0; n < 2; n++) {
    float bv = -3.0e38f; int br = 0;
    #pragma unroll
    for (int m = 0; m < 2; m++) {
      #pragma unroll
      for (int reg = 0; reg < 16; reg++) {
        float v = n == 0 ? (m == 0 ? acc00[reg] : acc10[reg])
                         : (m == 0 ? acc01[reg] : acc11[reg]);
        int lr = m * 32 + (reg & 3) + 8 * (reg >> 2);   // ascending over (m,reg)
        if (v > bv) { bv = v; br = lr; }
      }
    }
    u32 q = (u32)(brow + wr * 64 + br + 4 * hi);
    u64 key = ((u64)fkey(bv) << 32) | (u64)(0xFFFFFFFFu - q);
    u64 o = __shfl_xor(key, 32);
    key = key > o ? key : o;
    if (hi == 0) part[(size_t)(fbase + n * 32) * 512 + mslot] = key;
  }
}

// ---------------- kernel 3: reduce argmax partials -> nn_idx ----------------
__global__ void k_argmax_reduce(const u64* __restrict__ part, int* __restrict__ nnidx) {
  int row = (int)((blockIdx.x * blockDim.x + threadIdx.x) >> 6);
  int lane = threadIdx.x & 63;
  const u64* p = part + (size_t)row * 512;
  u64 best = 0;
  #pragma unroll
  for (int i = 0; i < 8; i++) { u64 v = p[lane * 8 + i]; best = best > v ? best : v; }
  #pragma unroll
  for (int off = 1; off < 64; off <<= 1) { u64 o = __shfl_xor(best, off); best = best > o ? best : o; }
  if (lane == 0) nnidx[row] = (int)(0xFFFFFFFFu - (u32)(best & 0xFFFFFFFFu));
}

// ---------------- kernel 3b: gather nn rows into pre-tiled nn8T ---------------
// nn8T[j] = queue8T row nnidx[j], kept in the fragment-tiled layout. A row's
// data = 32 chunks of 16B at (g>>5)*16384 + c*512 + (g&31)*16 (c = 0..31).
// 4096 rows x 32 chunks = 131072 copies; row-in-block fastest -> coalesced dst.
// This removes k_sim_gemm8's per-lane scattered gather (R15 regression: the
// same 128 rows were re-gathered for all 32 mt tiles).
__global__ void k_gather(const u8* __restrict__ queue8T, const int* __restrict__ nnidx,
                         u8* __restrict__ nn8T) {
  int T = (int)(blockIdx.x * blockDim.x + threadIdx.x);   // 131072
  int rb = T >> 10;            // output row-block 0..127
  int c  = (T >> 5) & 31;      // chunk 0..31
  int r  = T & 31;             // row-in-block
  int g = nnidx[rb * 32 + r];
  const uint4 v = *reinterpret_cast<const uint4*>(
      queue8T + (size_t)(g >> 5) * 16384 + c * 512 + (g & 31) * 16);
  *reinterpret_cast<uint4*>(nn8T + (size_t)rb * 16384 + c * 512 + r * 16) = v;
}

// ---------------- kernel 4: fp8 GEMM feat @ nn^T + fused col-lse + positives --
// Transposed like k_argmax_gemm8: A = feat tile (M, scanned), B = nn8T tile
// (N = lanes, contiguous pre-tiled -- same staging as argmax8's feat path).
// C[i][j] = feat_i . nn_j = sim[j][i]; per-row lse of sim = per-COLUMN of C =
// lane-local 2-pass max/sum-exp scan over the lane's 32 M-rows, then hi-pair
// online-softmax merge via shfl_xor(32) (verified R15). pos[j] = C[j^2048][j]
// captured in-scan (unique writer across the pair). lsep[j][mt*2+wr] -> k_lse.
__global__ __launch_bounds__(256, 2) void k_sim_gemm8(
    const u8* __restrict__ feat8T, const u8* __restrict__ nn8T,
    float2* __restrict__ lsep, float* __restrict__ pos) {
  __shared__ u8 lds[49152];
  const int tid = threadIdx.x;
  const int w = tid >> 6, lane = tid & 63;
  const int wr = w >> 1, wc = w & 1;
  const int l31 = lane & 31, hi = lane >> 5;
  const int bid = (int)blockIdx.x;
  const int wg = (bid & 7) * 128 + (bid >> 3);   // bijective XCD swizzle (1024 = 8x128)
  const int mt = wg >> 5, nt = wg & 31;
  const int mtb = mt * 128, ntb = nt * 128;

  const u8* pA = feat8T + (size_t)(mtb >> 5) * 16384 + (tid >> 7) * 16384 + (tid & 127) * 16;
  const u8* pB = nn8T   + (size_t)(ntb >> 5) * 16384 + (tid >> 7) * 16384 + (tid & 127) * 16;
  const u32 dA = (u32)(size_t)(las_ptr)&lds[tid * 16];
  const u32 dB = dA + 8192;

  const u32 aAd = (u32)(size_t)(las_ptr)&lds[wr * 4096 + hi * 1024 + l31 * 16];
  const u32 bAd = (u32)(size_t)(las_ptr)&lds[8192 + wc * 4096 + hi * 1024 + l31 * 16];

  f32x16_t acc00 = {}, acc01 = {}, acc10 = {}, acc11 = {};

  auto stage = [&](int b, int t) {
    const u32 base = (u32)(b * 16384);
    __builtin_amdgcn_global_load_lds((gas_ptr)(pA + t * 2048),         (las_ptr)(size_t)(dA + base), 16, 0, 0);
    __builtin_amdgcn_global_load_lds((gas_ptr)(pA + 32768 + t * 2048), (las_ptr)(size_t)(dA + base + 4096), 16, 0, 0);
    __builtin_amdgcn_global_load_lds((gas_ptr)(pB + t * 2048),         (las_ptr)(size_t)(dB + base), 16, 0, 0);
    __builtin_amdgcn_global_load_lds((gas_ptr)(pB + 32768 + t * 2048), (las_ptr)(size_t)(dB + base + 4096), 16, 0, 0);
  };

  FP8_MAIN_LOOP();

  // epilogue: per-column (lane pair = nn row j) lse over 64 feat rows,
  // scale by 1/T=2, diag mask, positive capture, hi-pair online-softmax merge.
  const int mslot = mt * 2 + wr;
  const int ibase = mtb + wr * 64 + 4 * hi;
  #pragma unroll
  for (int n = 0; n < 2; n++) {
    const int j = ntb + wc * 64 + n * 32 + l31;
    const int jp = j ^ NHALF;
    float mx = -3.0e38f;
    #pragma unroll
    for (int m = 0; m < 2; m++) {
      #pragma unroll
      for (int reg = 0; reg < 16; reg++) {
        float v = (n == 0 ? (m == 0 ? acc00[reg] : acc10[reg])
                          : (m == 0 ? acc01[reg] : acc11[reg])) * 2.0f;
        int i = ibase + m * 32 + (reg & 3) + 8 * (reg >> 2);
        if (i == jp) pos[j] = v;            // positive (unique writer; jp != j)
        if (i == j) v = -1.0e30f;           // diag mask
        mx = fmaxf(mx, v);
      }
    }
    float sm = 0.f;
    #pragma unroll
    for (int m = 0; m < 2; m++) {
      #pragma unroll
      for (int reg = 0; reg < 16; reg++) {
        float v = (n == 0 ? (m == 0 ? acc00[reg] : acc10[reg])
                          : (m == 0 ? acc01[reg] : acc11[reg])) * 2.0f;
        int i = ibase + m * 32 + (reg & 3) + 8 * (reg >> 2);
        if (i == j) v = -1.0e30f;
        sm += __expf(v - mx);
      }
    }
    // merge the hi pair (each lane scanned only 32 of the 64 rows)
    float mo = __shfl_xor(mx, 32);
    float so = __shfl_xor(sm, 32);
    float M = fmaxf(mx, mo);
    sm = sm * __expf(mx - M) + so * __expf(mo - M);
    if (hi == 0) lsep[(size_t)j * 64 + mslot] = make_float2(M, sm);
  }
}

// ---------------- kernel 5: per-row logsumexp merge ----------------
__global__ void k_lse(const float2* __restrict__ lsep, float* __restrict__ lse) {
  int row = (int)((blockIdx.x * blockDim.x + threadIdx.x) >> 6);
  int lane = threadIdx.x & 63;
  float2 p = lsep[(size_t)row * 64 + lane];
  float m = p.x, s = p.y;
  #pragma unroll
  for (int off = 1; off < 64; off <<= 1) {
    float mo = __shfl_xor(m, off), so = __shfl_xor(s, off);
    float M = fmaxf(m, mo);
    s = s * __expf(m - M) + so * __expf(mo - M);
    m = M;
  }
  if (lane == 0) lse[row] = m + __logf(s);
}

// ---------------- kernel 6: final scalar ----------------
__global__ void k_final(const float* __restrict__ lse, const float* __restrict__ pos,
                        float* __restrict__ out) {
  __shared__ float red[4];
  int tid = threadIdx.x;
  float a = 0.f;
  for (int i = tid; i < NFEAT; i += 256) a += lse[i] - pos[i];
  #pragma unroll
  for (int off = 32; off >= 1; off >>= 1) a += __shfl_xor(a, off);
  if ((tid & 63) == 0) red[tid >> 6] = a;
  __syncthreads();
  if (tid == 0) out[0] = (red[0] + red[1] + red[2] + red[3]) / (float)NFEAT;
}

extern "C" void kernel_launch(void* const* d_in, const int* in_sizes, int n_in,
                              void* d_out, int out_size, void* d_ws, size_t ws_size,
                              hipStream_t stream) {
  const float* zi    = (const float*)d_in[0];
  const float* zj    = (const float*)d_in[1];
  const float* queue = (const float*)d_in[2];
  float* out = (float*)d_out;
  char* ws = (char*)d_ws;

  // ws layout (bytes):
  u8*     queue8T = (u8*)(ws + 0);               // 32768*512   = 16777216
  u8*     feat8T  = (u8*)(ws + 16777216);        // 4096*512    = 2097152
  u8*     nn8T    = (u8*)(ws + 18874368);        // 4096*512    = 2097152
  u64*    part    = (u64*)(ws + 20971520);       // 4096*512*8  = 16777216
  int*    nnidx   = (int*)(ws + 37748736);       // 4096*4      = 16384
  float2* lsep    = (float2*)(ws + 37765120);    // 4096*64*8   = 2097152
  float*  pos     = (float*)(ws + 39862272);     // 4096*4      = 16384
  float*  lse     = (float*)(ws + 39878656);     // 4096*4      = 16384
  // total = 39895040 bytes (~38 MB)

  k_norm<<<9216, 256, 0, stream>>>(zi, zj, queue, feat8T, queue8T);
  k_argmax_gemm8<<<8192, 256, 0, stream>>>(feat8T, queue8T, part);
  k_argmax_reduce<<<1024, 256, 0, stream>>>(part, nnidx);
  k_gather<<<512, 256, 0, stream>>>(queue8T, nnidx, nn8T);
  k_sim_gemm8<<<1024, 256, 0, stream>>>(feat8T, nn8T, lsep, pos);
  k_lse<<<1024, 256, 0, stream>>>(lsep, lse);
  k_final<<<1, 256, 0, stream>>>(lse, pos, out);
}

// Round 17
// 109.523 us; speedup vs baseline: 1.3183x; 1.0406x over previous
//
#include <hip/hip_runtime.h>
#include <cstdint>

#define NFEAT 4096
#define NHALF 2048
#define DDIM  512
#define QROWS 32768

typedef unsigned short u16;
typedef unsigned char  u8;
typedef unsigned int   u32;
typedef unsigned long long u64;

typedef float  f32x16_t __attribute__((ext_vector_type(16)));
typedef int    i32x4_t  __attribute__((ext_vector_type(4)));
typedef int    i32x8_t  __attribute__((ext_vector_type(8)));

typedef const __attribute__((address_space(1))) void* gas_ptr;
typedef __attribute__((address_space(3))) void* las_ptr;

// monotonic unsigned encoding of float (no NaN/Inf expected)
__device__ __forceinline__ u32 fkey(float f) {
  u32 u = __float_as_uint(f);
  return (u & 0x80000000u) ? ~u : (u | 0x80000000u);
}

// ---------------- kernel 1: l2-normalize rows -> TILED fp8(e4m3) --------------
// fp8 buffers stored PRE-TILED in the GEMM's fragment order: addr(row,k) =
// (row>>5)*16384 + (k>>6)*2048 + ((k>>5)&1)*1024 + ((k>>4)&1)*512 +
// (row&31)*16 + (k&15).  (verified R11/R12, absmax 0.0)
__global__ void k_norm(const float* __restrict__ zi, const float* __restrict__ zj,
                       const float* __restrict__ queue,
                       u8* __restrict__ feat8T, u8* __restrict__ queue8T) {
  int gw = (int)((blockIdx.x * blockDim.x + threadIdx.x) >> 6);
  int lane = threadIdx.x & 63;
  const float* src; u8* dstT; int r31;
  if (gw < NFEAT) {
    src = (gw < NHALF) ? (zi + (size_t)gw * DDIM) : (zj + (size_t)(gw - NHALF) * DDIM);
    dstT = feat8T + (size_t)(gw >> 5) * 16384; r31 = gw & 31;
  } else {
    int r = gw - NFEAT;
    src = queue + (size_t)r * DDIM;
    dstT = queue8T + (size_t)(r >> 5) * 16384; r31 = r & 31;
  }
  float4 v0 = reinterpret_cast<const float4*>(src)[lane * 2];
  float4 v1 = reinterpret_cast<const float4*>(src)[lane * 2 + 1];
  float ss = v0.x*v0.x + v0.y*v0.y + v0.z*v0.z + v0.w*v0.w
           + v1.x*v1.x + v1.y*v1.y + v1.z*v1.z + v1.w*v1.w;
  #pragma unroll
  for (int off = 32; off >= 1; off >>= 1) ss += __shfl_xor(ss, off);
  float inv = 1.0f / fmaxf(sqrtf(ss), 1e-12f);
  float n0 = v0.x*inv, n1 = v0.y*inv, n2 = v0.z*inv, n3 = v0.w*inv;
  float n4 = v1.x*inv, n5 = v1.y*inv, n6 = v1.z*inv, n7 = v1.w*inv;
  u32 p01, p23, p45, p67;
  asm("v_cvt_pk_fp8_f32 %0, %1, %2" : "=v"(p01) : "v"(n0), "v"(n1));
  asm("v_cvt_pk_fp8_f32 %0, %1, %2" : "=v"(p23) : "v"(n2), "v"(n3));
  asm("v_cvt_pk_fp8_f32 %0, %1, %2" : "=v"(p45) : "v"(n4), "v"(n5));
  asm("v_cvt_pk_fp8_f32 %0, %1, %2" : "=v"(p67) : "v"(n6), "v"(n7));
  uint2 w8;
  w8.x = (p01 & 0xFFFFu) | (p23 << 16);
  w8.y = (p45 & 0xFFFFu) | (p67 << 16);
  size_t toff = (size_t)(lane >> 3) * 2048 + ((lane >> 2) & 1) * 1024
              + ((lane >> 1) & 1) * 512 + r31 * 16 + (lane & 1) * 8;
  *reinterpret_cast<uint2*>(dstT + toff) = w8;
}

#define SB0() __builtin_amdgcn_sched_barrier(0)
#define LGKM0_SB() do { asm volatile("s_waitcnt lgkmcnt(0)" ::: "memory"); SB0(); } while (0)
#define VMCNT4() asm volatile("s_waitcnt vmcnt(4)" ::: "memory")
#define VMCNT0() asm volatile("s_waitcnt vmcnt(0)" ::: "memory")
#define SBAR() __builtin_amdgcn_s_barrier()
#define RD(dst, base, off) asm volatile("ds_read_b128 %0, %1 offset:" off \
                                        : "=v"(dst) : "v"(base))
#define MFMA8(ACC, AV, BV) \
  ACC = __builtin_amdgcn_mfma_scale_f32_32x32x64_f8f6f4(AV, BV, ACC, 0, 0, 0, \
        0x7F7F7F7F, 0, 0x7F7F7F7F)

// ---------------- kernel 2: WIDE fp8 GEMM queue @ feat^T + fused col-argmax ---
// R17 geometry: block 128(M) x 256(N), 4 waves (2M x 2N), wave tile 64x128
// (2m x 4n of 32x32x64 f8f6f4, acc 128 regs). Each fragment feeds 8 MFMAs/wave
// -> LDS read traffic per output halves vs R12 (floor 55 -> ~31 us/CU).
// FRAGMENT-ORDERED LDS per buf: A 8KB (rb*2048 + hi_k*1024 + s*512 + r31*16),
// B 16KB (+8192, nb*2048 + ...). Ring-2 dbuf = 48KB -> 3 blocks/CU.
// Ledger: stage(t+1) at top of t (buf (t+1)&1's readers finished before t-1's
// ending barrier -> WAR safe); boundary vmcnt(0)+barrier ensures stage(t+1)
// landed (issued one full compute phase earlier). Epilogue = verified R12
// in-register col-argmax x 4 n-groups; part[f][mt*2+wr] (512 slots) unchanged.
__global__ __launch_bounds__(256, 2) void k_argmax_gemm8(
    const u8* __restrict__ feat8T, const u8* __restrict__ queue8T,
    u64* __restrict__ part) {
  __shared__ u8 lds[49152];
  const int tid = threadIdx.x;
  const int w = tid >> 6, lane = tid & 63;
  const int wr = w >> 1, wc = w & 1;
  const int l31 = lane & 31, hi = lane >> 5;
  const int bid = (int)blockIdx.x;
  const int wg = (bid & 7) * 512 + (bid >> 3);   // bijective XCD swizzle (4096 = 8x512)
  const int mt = wg >> 4, ft = wg & 15;          // ft fastest: 2MB queue slice/XCD
  const int brow = mt * 128, bcol = ft * 256;

  const u8* pA = queue8T + (size_t)(brow >> 5) * 16384 + (tid >> 7) * 16384 + (tid & 127) * 16;
  const u8* pB = feat8T  + (size_t)(bcol >> 5) * 16384 + (tid >> 7) * 16384 + (tid & 127) * 16;
  const u32 dA = (u32)(size_t)(las_ptr)&lds[tid * 16];
  const u32 dB = dA + 8192;

  // read bases: A rows (wave wr), B cols (wave wc = 128-col half)
  const u32 aAd = (u32)(size_t)(las_ptr)&lds[wr * 4096 + hi * 1024 + l31 * 16];
  const u32 bAd = (u32)(size_t)(las_ptr)&lds[8192 + wc * 8192 + hi * 1024 + l31 * 16];

  f32x16_t acc00 = {}, acc01 = {}, acc02 = {}, acc03 = {};
  f32x16_t acc10 = {}, acc11 = {}, acc12 = {}, acc13 = {};

  auto stage = [&](int b, int t) {
    const u32 base = (u32)(b * 24576);
    __builtin_amdgcn_global_load_lds((gas_ptr)(pA + t * 2048),         (las_ptr)(size_t)(dA + base), 16, 0, 0);
    __builtin_amdgcn_global_load_lds((gas_ptr)(pA + 32768 + t * 2048), (las_ptr)(size_t)(dA + base + 4096), 16, 0, 0);
    __builtin_amdgcn_global_load_lds((gas_ptr)(pB + t * 2048),         (las_ptr)(size_t)(dB + base), 16, 0, 0);
    __builtin_amdgcn_global_load_lds((gas_ptr)(pB + 32768 + t * 2048), (las_ptr)(size_t)(dB + base + 4096), 16, 0, 0);
    __builtin_amdgcn_global_load_lds((gas_ptr)(pB + 65536 + t * 2048), (las_ptr)(size_t)(dB + base + 8192), 16, 0, 0);
    __builtin_amdgcn_global_load_lds((gas_ptr)(pB + 98304 + t * 2048), (las_ptr)(size_t)(dB + base + 12288), 16, 0, 0);
  };

  stage(0, 0);
  VMCNT0();
  SBAR();

  #pragma unroll
  for (int t = 0; t < 8; t++) {
    if (t < 7) stage((t + 1) & 1, t + 1);
    const u32 bb = (u32)((t & 1) * 24576);
    const u32 xa = aAd + bb, xb = bAd + bb;
    i32x4_t r0, r1, r2, r3, s0, s1, s2, s3, s4, s5, s6, s7;
    RD(r0, xa, "0");    RD(r1, xa, "512");
    RD(r2, xa, "2048"); RD(r3, xa, "2560");
    RD(s0, xb, "0");    RD(s1, xb, "512");
    RD(s2, xb, "2048"); RD(s3, xb, "2560");
    RD(s4, xb, "4096"); RD(s5, xb, "4608");
    RD(s6, xb, "6144"); RD(s7, xb, "6656");
    LGKM0_SB();
    i32x8_t A0 = __builtin_shufflevector(r0, r1, 0, 1, 2, 3, 4, 5, 6, 7);
    i32x8_t A1 = __builtin_shufflevector(r2, r3, 0, 1, 2, 3, 4, 5, 6, 7);
    i32x8_t B0 = __builtin_shufflevector(s0, s1, 0, 1, 2, 3, 4, 5, 6, 7);
    i32x8_t B1 = __builtin_shufflevector(s2, s3, 0, 1, 2, 3, 4, 5, 6, 7);
    i32x8_t B2 = __builtin_shufflevector(s4, s5, 0, 1, 2, 3, 4, 5, 6, 7);
    i32x8_t B3 = __builtin_shufflevector(s6, s7, 0, 1, 2, 3, 4, 5, 6, 7);
    __builtin_amdgcn_s_setprio(1);
    MFMA8(acc00, A0, B0); MFMA8(acc01, A0, B1);
    MFMA8(acc02, A0, B2); MFMA8(acc03, A0, B3);
    MFMA8(acc10, A1, B0); MFMA8(acc11, A1, B1);
    MFMA8(acc12, A1, B2); MFMA8(acc13, A1, B3);
    __builtin_amdgcn_s_setprio(0);
    if (t < 7) { VMCNT0(); SBAR(); }
  }

  // epilogue: per-feature (column = lane pair) argmax over wave's 64 queue rows.
  // C/D 32x32: col = lane&31, row = (reg&3) + 8*(reg>>2) + 4*hi (+m*32).
  const int mslot = mt * 2 + wr;
#define AMAX_N(ACC0, ACC1, NOFF) do { \
    float bv = -3.0e38f; int br = 0; \
    _Pragma("unroll") \
    for (int reg = 0; reg < 16; reg++) { \
      float v = ACC0[reg]; int lr = (reg & 3) + 8 * (reg >> 2); \
      if (v > bv) { bv = v; br = lr; } } \
    _Pragma("unroll") \
    for (int reg = 0; reg < 16; reg++) { \
      float v = ACC1[reg]; int lr = 32 + (reg & 3) + 8 * (reg >> 2); \
      if (v > bv) { bv = v; br = lr; } } \
    u32 q = (u32)(brow + wr * 64 + br + 4 * hi); \
    u64 key = ((u64)fkey(bv) << 32) | (u64)(0xFFFFFFFFu - q); \
    u64 o = __shfl_xor(key, 32); \
    key = key > o ? key : o; \
    int j = bcol + wc * 128 + NOFF + l31; \
    if (hi == 0) part[(size_t)j * 512 + mslot] = key; \
  } while (0)
  AMAX_N(acc00, acc10, 0);
  AMAX_N(acc01, acc11, 32);
  AMAX_N(acc02, acc12, 64);
  AMAX_N(acc03, acc13, 96);
#undef AMAX_N
}

// ---------------- kernel 3: reduce argmax partials + FUSED row gather ---------
// One wave per feature row: u64-key butterfly over 512 partials (all lanes end
// with the max), then lanes 0-31 copy the winning queue row (32 x 16B chunks,
// fragment-tiled layout) into nn8T. Removes the separate k_gather launch.
__global__ void k_reduce_gather(const u64* __restrict__ part,
                                const u8* __restrict__ queue8T,
                                u8* __restrict__ nn8T) {
  int row = (int)((blockIdx.x * blockDim.x + threadIdx.x) >> 6);
  int lane = threadIdx.x & 63;
  const u64* p = part + (size_t)row * 512;
  u64 best = 0;
  #pragma unroll
  for (int i = 0; i < 8; i++) { u64 v = p[lane * 8 + i]; best = best > v ? best : v; }
  #pragma unroll
  for (int off = 1; off < 64; off <<= 1) { u64 o = __shfl_xor(best, off); best = best > o ? best : o; }
  int g = (int)(0xFFFFFFFFu - (u32)(best & 0xFFFFFFFFu));
  if (lane < 32) {
    const uint4 v = *reinterpret_cast<const uint4*>(
        queue8T + (size_t)(g >> 5) * 16384 + lane * 512 + (g & 31) * 16);
    *reinterpret_cast<uint4*>(
        nn8T + (size_t)(row >> 5) * 16384 + lane * 512 + (row & 31) * 16) = v;
  }
}

// ---------------- R12 tile engine (narrow, verified) for k_sim_gemm8 ----------
#define FP8_TILE(XA, XB) do { \
    i32x4_t a00, a01, a10, a11, b00, b01, b10, b11; \
    RD(a00, XA, "0"); RD(a01, XA, "512"); \
    RD(a10, XA, "2048"); RD(a11, XA, "2560"); \
    RD(b00, XB, "0"); RD(b01, XB, "512"); \
    RD(b10, XB, "2048"); RD(b11, XB, "2560"); \
    LGKM0_SB(); \
    i32x8_t A0 = __builtin_shufflevector(a00, a01, 0, 1, 2, 3, 4, 5, 6, 7); \
    i32x8_t A1 = __builtin_shufflevector(a10, a11, 0, 1, 2, 3, 4, 5, 6, 7); \
    i32x8_t B0 = __builtin_shufflevector(b00, b01, 0, 1, 2, 3, 4, 5, 6, 7); \
    i32x8_t B1 = __builtin_shufflevector(b10, b11, 0, 1, 2, 3, 4, 5, 6, 7); \
    __builtin_amdgcn_s_setprio(1); \
    MFMA8(acc00, A0, B0); \
    MFMA8(acc01, A0, B1); \
    MFMA8(acc10, A1, B0); \
    MFMA8(acc11, A1, B1); \
    __builtin_amdgcn_s_setprio(0); \
  } while (0)

#define FP8_MAIN_LOOP() do { \
  stage(0, 0); stage(1, 1); \
  VMCNT4(); \
  SBAR(); \
  _Pragma("unroll") \
  for (int t = 0; t < 8; t++) { \
    if (t <= 5) stage((t + 2) % 3, t + 2); \
    const u32 bb = (u32)((t % 3) * 16384); \
    FP8_TILE(aAd + bb, bAd + bb); \
    if (t < 7) { \
      if (t <= 5) VMCNT4(); else VMCNT0(); \
      SBAR(); \
    } \
  } } while (0)

// ---------------- kernel 4: fp8 GEMM feat @ nn^T + fused col-lse + positives --
// (verified R16: contiguous nn8T staging, lane-pair lse + hi merge)
__global__ __launch_bounds__(256, 2) void k_sim_gemm8(
    const u8* __restrict__ feat8T, const u8* __restrict__ nn8T,
    float2* __restrict__ lsep, float* __restrict__ pos) {
  __shared__ u8 lds[49152];
  const int tid = threadIdx.x;
  const int w = tid >> 6, lane = tid & 63;
  const int wr = w >> 1, wc = w & 1;
  const int l31 = lane & 31, hi = lane >> 5;
  const int bid = (int)blockIdx.x;
  const int wg = (bid & 7) * 128 + (bid >> 3);   // bijective XCD swizzle (1024 = 8x128)
  const int mt = wg >> 5, nt = wg & 31;
  const int mtb = mt * 128, ntb = nt * 128;

  const u8* pA = feat8T + (size_t)(mtb >> 5) * 16384 + (tid >> 7) * 16384 + (tid & 127) * 16;
  const u8* pB = nn8T   + (size_t)(ntb >> 5) * 16384 + (tid >> 7) * 16384 + (tid & 127) * 16;
  const u32 dA = (u32)(size_t)(las_ptr)&lds[tid * 16];
  const u32 dB = dA + 8192;

  const u32 aAd = (u32)(size_t)(las_ptr)&lds[wr * 4096 + hi * 1024 + l31 * 16];
  const u32 bAd = (u32)(size_t)(las_ptr)&lds[8192 + wc * 4096 + hi * 1024 + l31 * 16];

  f32x16_t acc00 = {}, acc01 = {}, acc10 = {}, acc11 = {};

  auto stage = [&](int b, int t) {
    const u32 base = (u32)(b * 16384);
    __builtin_amdgcn_global_load_lds((gas_ptr)(pA + t * 2048),         (las_ptr)(size_t)(dA + base), 16, 0, 0);
    __builtin_amdgcn_global_load_lds((gas_ptr)(pA + 32768 + t * 2048), (las_ptr)(size_t)(dA + base + 4096), 16, 0, 0);
    __builtin_amdgcn_global_load_lds((gas_ptr)(pB + t * 2048),         (las_ptr)(size_t)(dB + base), 16, 0, 0);
    __builtin_amdgcn_global_load_lds((gas_ptr)(pB + 32768 + t * 2048), (las_ptr)(size_t)(dB + base + 4096), 16, 0, 0);
  };

  FP8_MAIN_LOOP();

  // epilogue: per-column (lane pair = nn row j) lse over 64 feat rows,
  // scale by 1/T=2, diag mask, positive capture, hi-pair online-softmax merge.
  const int mslot = mt * 2 + wr;
  const int ibase = mtb + wr * 64 + 4 * hi;
  #pragma unroll
  for (int n = 0; n < 2; n++) {
    const int j = ntb + wc * 64 + n * 32 + l31;
    const int jp = j ^ NHALF;
    float mx = -3.0e38f;
    #pragma unroll
    for (int m = 0; m < 2; m++) {
      #pragma unroll
      for (int reg = 0; reg < 16; reg++) {
        float v = (n == 0 ? (m == 0 ? acc00[reg] : acc10[reg])
                          : (m == 0 ? acc01[reg] : acc11[reg])) * 2.0f;
        int i = ibase + m * 32 + (reg & 3) + 8 * (reg >> 2);
        if (i == jp) pos[j] = v;            // positive (unique writer; jp != j)
        if (i == j) v = -1.0e30f;           // diag mask
        mx = fmaxf(mx, v);
      }
    }
    float sm = 0.f;
    #pragma unroll
    for (int m = 0; m < 2; m++) {
      #pragma unroll
      for (int reg = 0; reg < 16; reg++) {
        float v = (n == 0 ? (m == 0 ? acc00[reg] : acc10[reg])
                          : (m == 0 ? acc01[reg] : acc11[reg])) * 2.0f;
        int i = ibase + m * 32 + (reg & 3) + 8 * (reg >> 2);
        if (i == j) v = -1.0e30f;
        sm += __expf(v - mx);
      }
    }
    // merge the hi pair (each lane scanned only 32 of the 64 rows)
    float mo = __shfl_xor(mx, 32);
    float so = __shfl_xor(sm, 32);
    float M = fmaxf(mx, mo);
    sm = sm * __expf(mx - M) + so * __expf(mo - M);
    if (hi == 0) lsep[(size_t)j * 64 + mslot] = make_float2(M, sm);
  }
}

// ---------------- kernel 5: per-row logsumexp merge ----------------
__global__ void k_lse(const float2* __restrict__ lsep, float* __restrict__ lse) {
  int row = (int)((blockIdx.x * blockDim.x + threadIdx.x) >> 6);
  int lane = threadIdx.x & 63;
  float2 p = lsep[(size_t)row * 64 + lane];
  float m = p.x, s = p.y;
  #pragma unroll
  for (int off = 1; off < 64; off <<= 1) {
    float mo = __shfl_xor(m, off), so = __shfl_xor(s, off);
    float M = fmaxf(m, mo);
    s = s * __expf(m - M) + so * __expf(mo - M);
    m = M;
  }
  if (lane == 0) lse[row] = m + __logf(s);
}

// ---------------- kernel 6: final scalar ----------------
__global__ void k_final(const float* __restrict__ lse, const float* __restrict__ pos,
                        float* __restrict__ out) {
  __shared__ float red[4];
  int tid = threadIdx.x;
  float a = 0.f;
  for (int i = tid; i < NFEAT; i += 256) a += lse[i] - pos[i];
  #pragma unroll
  for (int off = 32; off >= 1; off >>= 1) a += __shfl_xor(a, off);
  if ((tid & 63) == 0) red[tid >> 6] = a;
  __syncthreads();
  if (tid == 0) out[0] = (red[0] + red[1] + red[2] + red[3]) / (float)NFEAT;
}

extern "C" void kernel_launch(void* const* d_in, const int* in_sizes, int n_in,
                              void* d_out, int out_size, void* d_ws, size_t ws_size,
                              hipStream_t stream) {
  const float* zi    = (const float*)d_in[0];
  const float* zj    = (const float*)d_in[1];
  const float* queue = (const float*)d_in[2];
  float* out = (float*)d_out;
  char* ws = (char*)d_ws;

  // ws layout (bytes):
  u8*     queue8T = (u8*)(ws + 0);               // 32768*512   = 16777216
  u8*     feat8T  = (u8*)(ws + 16777216);        // 4096*512    = 2097152
  u8*     nn8T    = (u8*)(ws + 18874368);        // 4096*512    = 2097152
  u64*    part    = (u64*)(ws + 20971520);       // 4096*512*8  = 16777216
  float2* lsep    = (float2*)(ws + 37748736);    // 4096*64*8   = 2097152
  float*  pos     = (float*)(ws + 39845888);     // 4096*4      = 16384
  float*  lse     = (float*)(ws + 39862272);     // 4096*4      = 16384
  // total = 39878656 bytes (~38 MB)

  k_norm<<<9216, 256, 0, stream>>>(zi, zj, queue, feat8T, queue8T);
  k_argmax_gemm8<<<4096, 256, 0, stream>>>(feat8T, queue8T, part);
  k_reduce_gather<<<1024, 256, 0, stream>>>(part, queue8T, nn8T);
  k_sim_gemm8<<<1024, 256, 0, stream>>>(feat8T, nn8T, lsep, pos);
  k_lse<<<1024, 256, 0, stream>>>(lsep, lse);
  k_final<<<1, 256, 0, stream>>>(lse, pos, out);
}

// Round 18
// 109.436 us; speedup vs baseline: 1.3193x; 1.0008x over previous
//
#include <hip/hip_runtime.h>
#include <cstdint>

#define NFEAT 4096
#define NHALF 2048
#define DDIM  512
#define QROWS 32768

typedef unsigned short u16;
typedef unsigned char  u8;
typedef unsigned int   u32;
typedef unsigned long long u64;

typedef float  f32x16_t __attribute__((ext_vector_type(16)));
typedef int    i32x4_t  __attribute__((ext_vector_type(4)));
typedef int    i32x8_t  __attribute__((ext_vector_type(8)));

typedef const __attribute__((address_space(1))) void* gas_ptr;
typedef __attribute__((address_space(3))) void* las_ptr;

// monotonic unsigned encoding of float (no NaN/Inf expected)
__device__ __forceinline__ u32 fkey(float f) {
  u32 u = __float_as_uint(f);
  return (u & 0x80000000u) ? ~u : (u | 0x80000000u);
}

// ---------------- kernel 1: l2-normalize rows -> TILED fp8(e4m3) --------------
// fp8 buffers stored PRE-TILED in the GEMM's fragment order: addr(row,k) =
// (row>>5)*16384 + (k>>6)*2048 + ((k>>5)&1)*1024 + ((k>>4)&1)*512 +
// (row&31)*16 + (k&15).  (verified R11/R12, absmax 0.0)
__global__ void k_norm(const float* __restrict__ zi, const float* __restrict__ zj,
                       const float* __restrict__ queue,
                       u8* __restrict__ feat8T, u8* __restrict__ queue8T) {
  int gw = (int)((blockIdx.x * blockDim.x + threadIdx.x) >> 6);
  int lane = threadIdx.x & 63;
  const float* src; u8* dstT; int r31;
  if (gw < NFEAT) {
    src = (gw < NHALF) ? (zi + (size_t)gw * DDIM) : (zj + (size_t)(gw - NHALF) * DDIM);
    dstT = feat8T + (size_t)(gw >> 5) * 16384; r31 = gw & 31;
  } else {
    int r = gw - NFEAT;
    src = queue + (size_t)r * DDIM;
    dstT = queue8T + (size_t)(r >> 5) * 16384; r31 = r & 31;
  }
  float4 v0 = reinterpret_cast<const float4*>(src)[lane * 2];
  float4 v1 = reinterpret_cast<const float4*>(src)[lane * 2 + 1];
  float ss = v0.x*v0.x + v0.y*v0.y + v0.z*v0.z + v0.w*v0.w
           + v1.x*v1.x + v1.y*v1.y + v1.z*v1.z + v1.w*v1.w;
  #pragma unroll
  for (int off = 32; off >= 1; off >>= 1) ss += __shfl_xor(ss, off);
  float inv = 1.0f / fmaxf(sqrtf(ss), 1e-12f);
  float n0 = v0.x*inv, n1 = v0.y*inv, n2 = v0.z*inv, n3 = v0.w*inv;
  float n4 = v1.x*inv, n5 = v1.y*inv, n6 = v1.z*inv, n7 = v1.w*inv;
  u32 p01, p23, p45, p67;
  asm("v_cvt_pk_fp8_f32 %0, %1, %2" : "=v"(p01) : "v"(n0), "v"(n1));
  asm("v_cvt_pk_fp8_f32 %0, %1, %2" : "=v"(p23) : "v"(n2), "v"(n3));
  asm("v_cvt_pk_fp8_f32 %0, %1, %2" : "=v"(p45) : "v"(n4), "v"(n5));
  asm("v_cvt_pk_fp8_f32 %0, %1, %2" : "=v"(p67) : "v"(n6), "v"(n7));
  uint2 w8;
  w8.x = (p01 & 0xFFFFu) | (p23 << 16);
  w8.y = (p45 & 0xFFFFu) | (p67 << 16);
  size_t toff = (size_t)(lane >> 3) * 2048 + ((lane >> 2) & 1) * 1024
              + ((lane >> 1) & 1) * 512 + r31 * 16 + (lane & 1) * 8;
  *reinterpret_cast<uint2*>(dstT + toff) = w8;
}

#define SB0() __builtin_amdgcn_sched_barrier(0)
#define LGKM0_SB() do { asm volatile("s_waitcnt lgkmcnt(0)" ::: "memory"); SB0(); } while (0)
#define VMCNT4() asm volatile("s_waitcnt vmcnt(4)" ::: "memory")
#define VMCNT0() asm volatile("s_waitcnt vmcnt(0)" ::: "memory")
#define SBAR() __builtin_amdgcn_s_barrier()
#define RD(dst, base, off) asm volatile("ds_read_b128 %0, %1 offset:" off \
                                        : "=v"(dst) : "v"(base))
#define MFMA8(ACC, AV, BV) \
  ACC = __builtin_amdgcn_mfma_scale_f32_32x32x64_f8f6f4(AV, BV, ACC, 0, 0, 0, \
        0x7F7F7F7F, 0, 0x7F7F7F7F)

// ---------------- kernel 2: fp8 GEMM queue @ feat^T + fused col-argmax --------
// R18 structure: block 512 thr = 8 waves (2M x 4N), wave tile 64x64 (acc 64
// regs), block tile 128(M) x 256(N). A (queue rows, reused by 4 waves) staged
// in LDS: 8KB/tile, ring-2 = 16KB. B (feat cols, reused by only 2 waves)
// loaded per-lane DIRECT from the pre-tiled global buffer into registers (the
// tiled layout makes a B fragment = two contiguous 16B per lane) -- no LDS,
// no barrier, compiler-tracked vmcnt. Regs ~116 -> 4 waves/SIMD. Ledger:
// stage A(t+1) at top of t (WAR: buf (t+1)&1's readers lgkm-confirmed before
// t-1's ending barrier); end-of-t vmcnt(0)+barrier proves it landed.
// Epilogue = verified R12 in-register col-argmax (wave cols = bcol + wc*64).
__global__ __launch_bounds__(512, 3) void k_argmax_gemm8(
    const u8* __restrict__ feat8T, const u8* __restrict__ queue8T,
    u64* __restrict__ part) {
  __shared__ u8 lds[16384];
  const int tid = threadIdx.x;
  const int w = tid >> 6, lane = tid & 63;
  const int wr = w >> 2, wc = w & 3;          // 2M x 4N waves
  const int l31 = lane & 31, hi = lane >> 5;
  const int bid = (int)blockIdx.x;
  const int wg = (bid & 7) * 512 + (bid >> 3);   // bijective XCD swizzle (4096 = 8x512)
  const int mt = wg >> 4, ft = wg & 15;          // ft fastest: queue slice L2-resident
  const int brow = mt * 128, bcol = ft * 256;

  // A staging: thread stages 16B (row-block tid>>7, inner tid&127); dest linear
  const u8* pA = queue8T + (size_t)((brow >> 5) + (tid >> 7)) * 16384 + (tid & 127) * 16;
  const u32 dA = (u32)(size_t)(las_ptr)&lds[tid * 16];

  // A read base: frag m at offsets {0,512} (m=0), {2048,2560} (m=1); buf +8192
  const u32 aAd = (u32)(size_t)(las_ptr)&lds[wr * 4096 + hi * 1024 + l31 * 16];

  // B direct-load bases: col-blocks (bcol>>5)+wc*2 and +1; per-tile advance 2048
  const u8* pB0 = feat8T + (size_t)((bcol >> 5) + wc * 2) * 16384 + hi * 1024 + l31 * 16;
  const u8* pB1 = pB0 + 16384;

  f32x16_t acc00 = {}, acc01 = {}, acc10 = {}, acc11 = {};

  auto stageA = [&](int b, int t) {
    __builtin_amdgcn_global_load_lds((gas_ptr)(pA + t * 2048),
        (las_ptr)(size_t)(dA + (u32)(b * 8192)), 16, 0, 0);
  };

  stageA(0, 0);
  VMCNT0();
  SBAR();

  #pragma unroll
  for (int t = 0; t < 8; t++) {
    // B loads first (longest latency), then next-tile A stage, then A ds_reads
    const u8* q0 = pB0 + t * 2048;
    const u8* q1 = pB1 + t * 2048;
    i32x4_t b0l = *reinterpret_cast<const i32x4_t*>(q0);
    i32x4_t b0h = *reinterpret_cast<const i32x4_t*>(q0 + 512);
    i32x4_t b1l = *reinterpret_cast<const i32x4_t*>(q1);
    i32x4_t b1h = *reinterpret_cast<const i32x4_t*>(q1 + 512);
    if (t < 7) stageA((t + 1) & 1, t + 1);
    const u32 xa = aAd + (u32)((t & 1) * 8192);
    i32x4_t a0l, a0h, a1l, a1h;
    RD(a0l, xa, "0");    RD(a0h, xa, "512");
    RD(a1l, xa, "2048"); RD(a1h, xa, "2560");
    LGKM0_SB();
    i32x8_t A0 = __builtin_shufflevector(a0l, a0h, 0, 1, 2, 3, 4, 5, 6, 7);
    i32x8_t A1 = __builtin_shufflevector(a1l, a1h, 0, 1, 2, 3, 4, 5, 6, 7);
    i32x8_t B0 = __builtin_shufflevector(b0l, b0h, 0, 1, 2, 3, 4, 5, 6, 7);
    i32x8_t B1 = __builtin_shufflevector(b1l, b1h, 0, 1, 2, 3, 4, 5, 6, 7);
    __builtin_amdgcn_s_setprio(1);
    MFMA8(acc00, A0, B0); MFMA8(acc01, A0, B1);
    MFMA8(acc10, A1, B0); MFMA8(acc11, A1, B1);
    __builtin_amdgcn_s_setprio(0);
    if (t < 7) { VMCNT0(); SBAR(); }
  }

  // epilogue: per-feature (column = lane pair) argmax over wave's 64 queue rows.
  // C/D 32x32: col = lane&31, row = (reg&3) + 8*(reg>>2) + 4*hi (+m*32).
  const int mslot = mt * 2 + wr;
#define AMAX_N(ACC0, ACC1, NOFF) do { \
    float bv = -3.0e38f; int br = 0; \
    _Pragma("unroll") \
    for (int reg = 0; reg < 16; reg++) { \
      float v = ACC0[reg]; int lr = (reg & 3) + 8 * (reg >> 2); \
      if (v > bv) { bv = v; br = lr; } } \
    _Pragma("unroll") \
    for (int reg = 0; reg < 16; reg++) { \
      float v = ACC1[reg]; int lr = 32 + (reg & 3) + 8 * (reg >> 2); \
      if (v > bv) { bv = v; br = lr; } } \
    u32 q = (u32)(brow + wr * 64 + br + 4 * hi); \
    u64 key = ((u64)fkey(bv) << 32) | (u64)(0xFFFFFFFFu - q); \
    u64 o = __shfl_xor(key, 32); \
    key = key > o ? key : o; \
    int j = bcol + wc * 64 + NOFF + l31; \
    if (hi == 0) part[(size_t)j * 512 + mslot] = key; \
  } while (0)
  AMAX_N(acc00, acc10, 0);
  AMAX_N(acc01, acc11, 32);
#undef AMAX_N
}

// ---------------- kernel 3: reduce argmax partials + FUSED row gather ---------
__global__ void k_reduce_gather(const u64* __restrict__ part,
                                const u8* __restrict__ queue8T,
                                u8* __restrict__ nn8T) {
  int row = (int)((blockIdx.x * blockDim.x + threadIdx.x) >> 6);
  int lane = threadIdx.x & 63;
  const u64* p = part + (size_t)row * 512;
  u64 best = 0;
  #pragma unroll
  for (int i = 0; i < 8; i++) { u64 v = p[lane * 8 + i]; best = best > v ? best : v; }
  #pragma unroll
  for (int off = 1; off < 64; off <<= 1) { u64 o = __shfl_xor(best, off); best = best > o ? best : o; }
  int g = (int)(0xFFFFFFFFu - (u32)(best & 0xFFFFFFFFu));
  if (lane < 32) {
    const uint4 v = *reinterpret_cast<const uint4*>(
        queue8T + (size_t)(g >> 5) * 16384 + lane * 512 + (g & 31) * 16);
    *reinterpret_cast<uint4*>(
        nn8T + (size_t)(row >> 5) * 16384 + lane * 512 + (row & 31) * 16) = v;
  }
}

// ---------------- R12 tile engine (narrow, verified) for k_sim_gemm8 ----------
#define FP8_TILE(XA, XB) do { \
    i32x4_t a00, a01, a10, a11, b00, b01, b10, b11; \
    RD(a00, XA, "0"); RD(a01, XA, "512"); \
    RD(a10, XA, "2048"); RD(a11, XA, "2560"); \
    RD(b00, XB, "0"); RD(b01, XB, "512"); \
    RD(b10, XB, "2048"); RD(b11, XB, "2560"); \
    LGKM0_SB(); \
    i32x8_t A0 = __builtin_shufflevector(a00, a01, 0, 1, 2, 3, 4, 5, 6, 7); \
    i32x8_t A1 = __builtin_shufflevector(a10, a11, 0, 1, 2, 3, 4, 5, 6, 7); \
    i32x8_t B0 = __builtin_shufflevector(b00, b01, 0, 1, 2, 3, 4, 5, 6, 7); \
    i32x8_t B1 = __builtin_shufflevector(b10, b11, 0, 1, 2, 3, 4, 5, 6, 7); \
    __builtin_amdgcn_s_setprio(1); \
    MFMA8(acc00, A0, B0); \
    MFMA8(acc01, A0, B1); \
    MFMA8(acc10, A1, B0); \
    MFMA8(acc11, A1, B1); \
    __builtin_amdgcn_s_setprio(0); \
  } while (0)

#define FP8_MAIN_LOOP() do { \
  stage(0, 0); stage(1, 1); \
  VMCNT4(); \
  SBAR(); \
  _Pragma("unroll") \
  for (int t = 0; t < 8; t++) { \
    if (t <= 5) stage((t + 2) % 3, t + 2); \
    const u32 bb = (u32)((t % 3) * 16384); \
    FP8_TILE(aAd + bb, bAd + bb); \
    if (t < 7) { \
      if (t <= 5) VMCNT4(); else VMCNT0(); \
      SBAR(); \
    } \
  } } while (0)

// ---------------- kernel 4: fp8 GEMM feat @ nn^T + fused col-lse + positives --
// (verified R16: contiguous nn8T staging, lane-pair lse + hi merge)
__global__ __launch_bounds__(256, 2) void k_sim_gemm8(
    const u8* __restrict__ feat8T, const u8* __restrict__ nn8T,
    float2* __restrict__ lsep, float* __restrict__ pos) {
  __shared__ u8 lds[49152];
  const int tid = threadIdx.x;
  const int w = tid >> 6, lane = tid & 63;
  const int wr = w >> 1, wc = w & 1;
  const int l31 = lane & 31, hi = lane >> 5;
  const int bid = (int)blockIdx.x;
  const int wg = (bid & 7) * 128 + (bid >> 3);   // bijective XCD swizzle (1024 = 8x128)
  const int mt = wg >> 5, nt = wg & 31;
  const int mtb = mt * 128, ntb = nt * 128;

  const u8* pA = feat8T + (size_t)(mtb >> 5) * 16384 + (tid >> 7) * 16384 + (tid & 127) * 16;
  const u8* pB = nn8T   + (size_t)(ntb >> 5) * 16384 + (tid >> 7) * 16384 + (tid & 127) * 16;
  const u32 dA = (u32)(size_t)(las_ptr)&lds[tid * 16];
  const u32 dB = dA + 8192;

  const u32 aAd = (u32)(size_t)(las_ptr)&lds[wr * 4096 + hi * 1024 + l31 * 16];
  const u32 bAd = (u32)(size_t)(las_ptr)&lds[8192 + wc * 4096 + hi * 1024 + l31 * 16];

  f32x16_t acc00 = {}, acc01 = {}, acc10 = {}, acc11 = {};

  auto stage = [&](int b, int t) {
    const u32 base = (u32)(b * 16384);
    __builtin_amdgcn_global_load_lds((gas_ptr)(pA + t * 2048),         (las_ptr)(size_t)(dA + base), 16, 0, 0);
    __builtin_amdgcn_global_load_lds((gas_ptr)(pA + 32768 + t * 2048), (las_ptr)(size_t)(dA + base + 4096), 16, 0, 0);
    __builtin_amdgcn_global_load_lds((gas_ptr)(pB + t * 2048),         (las_ptr)(size_t)(dB + base), 16, 0, 0);
    __builtin_amdgcn_global_load_lds((gas_ptr)(pB + 32768 + t * 2048), (las_ptr)(size_t)(dB + base + 4096), 16, 0, 0);
  };

  FP8_MAIN_LOOP();

  // epilogue: per-column (lane pair = nn row j) lse over 64 feat rows,
  // scale by 1/T=2, diag mask, positive capture, hi-pair online-softmax merge.
  const int mslot = mt * 2 + wr;
  const int ibase = mtb + wr * 64 + 4 * hi;
  #pragma unroll
  for (int n = 0; n < 2; n++) {
    const int j = ntb + wc * 64 + n * 32 + l31;
    const int jp = j ^ NHALF;
    float mx = -3.0e38f;
    #pragma unroll
    for (int m = 0; m < 2; m++) {
      #pragma unroll
      for (int reg = 0; reg < 16; reg++) {
        float v = (n == 0 ? (m == 0 ? acc00[reg] : acc10[reg])
                          : (m == 0 ? acc01[reg] : acc11[reg])) * 2.0f;
        int i = ibase + m * 32 + (reg & 3) + 8 * (reg >> 2);
        if (i == jp) pos[j] = v;            // positive (unique writer; jp != j)
        if (i == j) v = -1.0e30f;           // diag mask
        mx = fmaxf(mx, v);
      }
    }
    float sm = 0.f;
    #pragma unroll
    for (int m = 0; m < 2; m++) {
      #pragma unroll
      for (int reg = 0; reg < 16; reg++) {
        float v = (n == 0 ? (m == 0 ? acc00[reg] : acc10[reg])
                          : (m == 0 ? acc01[reg] : acc11[reg])) * 2.0f;
        int i = ibase + m * 32 + (reg & 3) + 8 * (reg >> 2);
        if (i == j) v = -1.0e30f;
        sm += __expf(v - mx);
      }
    }
    // merge the hi pair (each lane scanned only 32 of the 64 rows)
    float mo = __shfl_xor(mx, 32);
    float so = __shfl_xor(sm, 32);
    float M = fmaxf(mx, mo);
    sm = sm * __expf(mx - M) + so * __expf(mo - M);
    if (hi == 0) lsep[(size_t)j * 64 + mslot] = make_float2(M, sm);
  }
}

// ---------------- kernel 5: per-row logsumexp merge ----------------
__global__ void k_lse(const float2* __restrict__ lsep, float* __restrict__ lse) {
  int row = (int)((blockIdx.x * blockDim.x + threadIdx.x) >> 6);
  int lane = threadIdx.x & 63;
  float2 p = lsep[(size_t)row * 64 + lane];
  float m = p.x, s = p.y;
  #pragma unroll
  for (int off = 1; off < 64; off <<= 1) {
    float mo = __shfl_xor(m, off), so = __shfl_xor(s, off);
    float M = fmaxf(m, mo);
    s = s * __expf(m - M) + so * __expf(mo - M);
    m = M;
  }
  if (lane == 0) lse[row] = m + __logf(s);
}

// ---------------- kernel 6: final scalar ----------------
__global__ void k_final(const float* __restrict__ lse, const float* __restrict__ pos,
                        float* __restrict__ out) {
  __shared__ float red[4];
  int tid = threadIdx.x;
  float a = 0.f;
  for (int i = tid; i < NFEAT; i += 256) a += lse[i] - pos[i];
  #pragma unroll
  for (int off = 32; off >= 1; off >>= 1) a += __shfl_xor(a, off);
  if ((tid & 63) == 0) red[tid >> 6] = a;
  __syncthreads();
  if (tid == 0) out[0] = (red[0] + red[1] + red[2] + red[3]) / (float)NFEAT;
}

extern "C" void kernel_launch(void* const* d_in, const int* in_sizes, int n_in,
                              void* d_out, int out_size, void* d_ws, size_t ws_size,
                              hipStream_t stream) {
  const float* zi    = (const float*)d_in[0];
  const float* zj    = (const float*)d_in[1];
  const float* queue = (const float*)d_in[2];
  float* out = (float*)d_out;
  char* ws = (char*)d_ws;

  // ws layout (bytes):
  u8*     queue8T = (u8*)(ws + 0);               // 32768*512   = 16777216
  u8*     feat8T  = (u8*)(ws + 16777216);        // 4096*512    = 2097152
  u8*     nn8T    = (u8*)(ws + 18874368);        // 4096*512    = 2097152
  u64*    part    = (u64*)(ws + 20971520);       // 4096*512*8  = 16777216
  float2* lsep    = (float2*)(ws + 37748736);    // 4096*64*8   = 2097152
  float*  pos     = (float*)(ws + 39845888);     // 4096*4      = 16384
  float*  lse     = (float*)(ws + 39862272);     // 4096*4      = 16384
  // total = 39878656 bytes (~38 MB)

  k_norm<<<9216, 256, 0, stream>>>(zi, zj, queue, feat8T, queue8T);
  k_argmax_gemm8<<<4096, 512, 0, stream>>>(feat8T, queue8T, part);
  k_reduce_gather<<<1024, 256, 0, stream>>>(part, queue8T, nn8T);
  k_sim_gemm8<<<1024, 256, 0, stream>>>(feat8T, nn8T, lsep, pos);
  k_lse<<<1024, 256, 0, stream>>>(lsep, lse);
  k_final<<<1, 256, 0, stream>>>(lse, pos, out);
}